// Round 1
// 152.786 us; speedup vs baseline: 1.0737x; 1.0737x over previous
//
#include <hip/hip_runtime.h>

// GNN surrogate — r18: K=32 MFMA upgrade via prep-side row permutation.
// r17 counters: MfmaUtil 40%, VALUBusy 27%, HBM 1.7%, occ 21% -> compute-bound
// on the MFMA pipe at the legacy half-rate 16x16x16 shape (4 cyc/CU per 8192
// FLOP vs 4.85 cyc/CU per 16384 FLOP for 16x16x32).
// Key identity: 16x16x32f16 C/D layout == 16x16x16 C/D layout, and its A/B
// operands take k = 8*quad + j (8 contiguous k per lane, ref-checked m92/m93).
// So half8 cat(fragLo, fragHi) of two K=16 C-frags is a valid K=32 operand up
// to the fixed bijection lambda(8q+j) = (j<4 ? 4q+j : 16+4q+(j-4)), which is
// folded into the B tiles (adjb, mb) at prep time -> zero runtime cost.
// MFMA/wave: 336 -> 176 (G: 128->64 each, L1/L2: 32->16 each, L0 unchanged).
// Kept __launch_bounds__(256,2): (256,3)'s 168-reg budget spilled in r15/r16;
// revisit occupancy only after this lands.

typedef _Float16 f16;
typedef __attribute__((ext_vector_type(8))) _Float16 half8;
typedef __attribute__((ext_vector_type(4))) _Float16 half4;
typedef __attribute__((ext_vector_type(2))) __fp16 fp16x2;
typedef __attribute__((ext_vector_type(4))) float f32x4;

namespace {
constexpr int N = 128, H = 32;
constexpr int WS_ADJB = 0;       // f16 [8gi][4c][64lane][8] K=32 adj B-tiles (32768 B)
constexpr int WS_W0B  = 32768;   // f16 [2t][64lane][4]  W1eff K=16 B-tiles   (1024 B)
constexpr int WS_MB   = 33792;   // f16 [2l][2t][64lane][8] Meff K=32 B-tiles (4096 B)
constexpr int WS_BIAS = 37888;   // f32 [3][32]
constexpr int WS_V    = 38400;   // f32 [128]
constexpr int WS_U    = 38912;   // f32 [32]
constexpr int WS_C    = 39040;   // f32 [1]
}

static __device__ __forceinline__ half4 pk4(float a, float b, float c, float d) {
  union { half4 v; fp16x2 h[2]; } u;
  u.h[0] = __builtin_amdgcn_cvt_pkrtz(a, b);
  u.h[1] = __builtin_amdgcn_cvt_pkrtz(c, d);
  return u.v;
}
static __device__ __forceinline__ half4 relupk(f32x4 c) {
  const half4 z = {};
  return __builtin_elementwise_max(pk4(c[0], c[1], c[2], c[3]), z);
}
static __device__ __forceinline__ half4 pkc(f32x4 c) {
  return pk4(c[0], c[1], c[2], c[3]);
}
static __device__ __forceinline__ half8 cat(half4 lo, half4 hi) {
  return __builtin_shufflevector(lo, hi, 0, 1, 2, 3, 4, 5, 6, 7);
}

#define MF(A, B, C)   __builtin_amdgcn_mfma_f32_16x16x16f16((A), (B), (C), 0, 0, 0)
#define MF32(A, B, C) __builtin_amdgcn_mfma_f32_16x16x32_f16((A), (B), (C), 0, 0, 0)

// ---- prep: block 1 fills adjb; block 0 does everything else ----
__global__ void prep(const float* __restrict__ adj,
                     const float* __restrict__ W_lift,
                     const float* __restrict__ b_lift,
                     const float* __restrict__ W1,
                     const float* __restrict__ b1,
                     const float* __restrict__ W2,
                     const float* __restrict__ b2,
                     const float* __restrict__ W_ro,
                     const float* __restrict__ b_ro,
                     char* __restrict__ ws) {
  const int tid = threadIdx.x;
  f16* adjb  = (f16*)(ws + WS_ADJB);
  f16* w0b   = (f16*)(ws + WS_W0B);
  f16* mb    = (f16*)(ws + WS_MB);
  float* bia = (float*)(ws + WS_BIAS);
  float* v   = (float*)(ws + WS_V);
  float* u   = (float*)(ws + WS_U);
  float* cp  = (float*)(ws + WS_C);

  if (blockIdx.x != 0) {
    // K=32 adjacency B-tiles. Hardware reads lane(q,lr) elem j as k=8q+j;
    // store adj column lambda(8q+j) there so the concat'd A-frags line up.
    for (int e = tid; e < 2048; e += 256) {
      const int gi = e >> 8, c = (e >> 6) & 3, lane = e & 63;
      const int lr = lane & 15, q = lane >> 4;
      const float* src = adj + (gi * 16 + lr) * N + c * 32;
      f16* dst = adjb + e * 8;
#pragma unroll
      for (int j = 0; j < 8; ++j) {
        const int col = (j < 4) ? (4 * q + j) : (12 + 4 * q + j);  // lambda
        dst[j] = (f16)src[col];
      }
    }
    return;
  }

  __shared__ float tmp[3][H][H];
  __shared__ float sred[N];
  for (int idx = tid; idx < 3 * H * H; idx += 256) {
    const int l = idx >> 10, rem = idx & 1023;
    const int k = rem >> 5, fo = rem & 31;
    float val = 0.f;
    if (l == 0) {
      if (k < 3) for (int c = 0; c < H; ++c) val += W_lift[k * H + c] * W1[c * H + fo];
    } else {
      const float* w2l = W2 + (l - 1) * H * H;
      const float* w1n = W1 + l * H * H;
      for (int c = 0; c < H; ++c) val += w2l[k * H + c] * w1n[c * H + fo];
    }
    tmp[l][k][fo] = val;
  }
  if (tid < N) {
    float s = 0.f;
    for (int i = 0; i < N; ++i) s += adj[i * N + tid];
    v[tid] = s * (1.0f / N);
    sred[tid] = s * (1.0f / N);
  }
  if (tid < H) {
    float s0 = b1[tid], s1 = b1[H + tid], s2 = b1[2 * H + tid];
    for (int c = 0; c < H; ++c) {
      s0 += b_lift[c] * W1[c * H + tid];
      s1 += b2[c] * W1[H * H + c * H + tid];
      s2 += b2[H + c] * W1[2 * H * H + c * H + tid];
    }
    bia[tid] = s0; bia[H + tid] = s1; bia[2 * H + tid] = s2;
    float su = 0.f;
    for (int c = 0; c < H; ++c) su += W2[2 * H * H + tid * H + c] * W_ro[c];
    u[tid] = su;
  }
  __syncthreads();
  // L0 B-tiles stay K=16 (only 3 live features).
  for (int e = tid; e < 512; e += 256) {
    const int t = e >> 8, lane = (e >> 2) & 63, j = e & 3;
    const int lr = lane & 15, q = lane >> 4;
    w0b[e] = (f16)tmp[0][q * 4 + j][t * 16 + lr];
  }
  // Meff K=32 B-tiles with lambda-permuted rows: [2l][2t][64lane][8].
  for (int e = tid; e < 2048; e += 256) {
    const int l = e >> 10, rem = e & 1023;
    const int t = rem >> 9, lane = (rem >> 3) & 63, j = rem & 7;
    const int lr = lane & 15, q = lane >> 4;
    const int k = (j < 4) ? (4 * q + j) : (12 + 4 * q + j);  // lambda
    mb[e] = (f16)tmp[1 + l][k][t * 16 + lr];
  }
  if (tid < 64) {
    float s = sred[tid] + sred[64 + tid];
#pragma unroll
    for (int off = 32; off > 0; off >>= 1) s += __shfl_down(s, off, 64);
    if (tid == 0) {
      float c2r = 0.f;
      for (int k = 0; k < H; ++k) c2r += b2[2 * H + k] * W_ro[k];
      cp[0] = c2r * s + b_ro[0];
    }
  }
}

__global__ __launch_bounds__(256, 2)
void gnn_mfma(const float* __restrict__ x,
              const char* __restrict__ ws,
              float* __restrict__ out) {
  const f16* adjb  = (const f16*)(ws + WS_ADJB);
  const f16* w0b   = (const f16*)(ws + WS_W0B);
  const f16* mb    = (const f16*)(ws + WS_MB);
  const float* bia = (const float*)(ws + WS_BIAS);
  const float* v   = (const float*)(ws + WS_V);
  const float* u   = (const float*)(ws + WS_U);
  const float* cp  = (const float*)(ws + WS_C);

  const int tid  = threadIdx.x;
  const int wave = tid >> 6;
  const int lane = tid & 63;
  const int lrow = lane & 15;
  const int quad = lane >> 4;
  const int b    = blockIdx.x * 4 + wave;

  const f32x4 zero = {0.f, 0.f, 0.f, 0.f};

  half4 tf00, tf01, tf10, tf11, tf20, tf21, tf30, tf31,
        tf40, tf41, tf50, tf51, tf60, tf61, tf70, tf71;
  half4 pf00, pf01, pf02, pf03, pf04, pf05, pf06, pf07,
        pf10, pf11, pf12, pf13, pf14, pf15, pf16, pf17;

  // ---- L0: T0[node][fout] = relu(x·W1eff + b0), K=16 MFMA ----
  {
    const half4 w0 = *(const half4*)(w0b + (0 * 64 + lane) * 4);
    const half4 w1 = *(const half4*)(w0b + (1 * 64 + lane) * 4);
    const float bb0 = bia[lrow], bb1 = bia[16 + lrow];
    const f32x4 bi0 = {bb0, bb0, bb0, bb0};
    const f32x4 bi1 = {bb1, bb1, bb1, bb1};
#define L0G(g, TF0, TF1)                                                     \
    {                                                                        \
      half4 xa = {};                                                         \
      if (quad == 0) {                                                       \
        const float* xr = x + ((size_t)b * N + (g) * 16 + lrow) * 3;         \
        xa = pk4(xr[0], xr[1], xr[2], 0.f);                                  \
      }                                                                      \
      TF0 = relupk(MF(xa, w0, bi0));                                         \
      TF1 = relupk(MF(xa, w1, bi1));                                         \
    }
    L0G(0, tf00, tf01) L0G(1, tf10, tf11) L0G(2, tf20, tf21) L0G(3, tf30, tf31)
    L0G(4, tf40, tf41) L0G(5, tf50, tf51) L0G(6, tf60, tf61) L0G(7, tf70, tf71)
#undef L0G
  }

  // G: P^T[fout t][node gi] — K=32 MFMAs. A-frags: half8 concat of two K=16
  // C-frags (nodes 32c..32c+31 via lambda); B: adjb tiles (lambda pre-folded).
  // Same B tile feeds both fout blocks.
#define GSTEP(gi, P0, P1)                                                    \
  {                                                                          \
    f32x4 a0 = zero, a1 = zero;                                              \
    const f16* ab = adjb + ((gi) * 256 + lane) * 8;                          \
    half8 bt;                                                                \
    bt = *(const half8*)(ab + 0 * 512);                                      \
    a0 = MF32(ca0, bt, a0); a1 = MF32(cb0, bt, a1);                          \
    bt = *(const half8*)(ab + 1 * 512);                                      \
    a0 = MF32(ca1, bt, a0); a1 = MF32(cb1, bt, a1);                          \
    bt = *(const half8*)(ab + 2 * 512);                                      \
    a0 = MF32(ca2, bt, a0); a1 = MF32(cb2, bt, a1);                          \
    bt = *(const half8*)(ab + 3 * 512);                                      \
    a0 = MF32(ca3, bt, a0); a1 = MF32(cb3, bt, a1);                          \
    P0 = pkc(a0); P1 = pkc(a1);                                              \
  }
#define GALL()                                                               \
  {                                                                          \
    const half8 ca0 = cat(tf00, tf10), ca1 = cat(tf20, tf30),                \
                ca2 = cat(tf40, tf50), ca3 = cat(tf60, tf70);                \
    const half8 cb0 = cat(tf01, tf11), cb1 = cat(tf21, tf31),                \
                cb2 = cat(tf41, tf51), cb3 = cat(tf61, tf71);                \
    GSTEP(0, pf00, pf10) GSTEP(1, pf01, pf11) GSTEP(2, pf02, pf12)           \
    GSTEP(3, pf03, pf13) GSTEP(4, pf04, pf14) GSTEP(5, pf05, pf15)           \
    GSTEP(6, pf06, pf16) GSTEP(7, pf07, pf17)                                \
  }

  GALL()   // G0

  // L1: T1 = relu(P·Meff1 + c1) — one K=32 MFMA per output block.
  {
    const f16* mbl = mb + 0 * 1024;
    const half8 m0 = *(const half8*)(mbl + (0 * 64 + lane) * 8);
    const half8 m1 = *(const half8*)(mbl + (1 * 64 + lane) * 8);
    const float bb0 = bia[H + lrow], bb1 = bia[H + 16 + lrow];
    const f32x4 bi0 = {bb0, bb0, bb0, bb0};
    const f32x4 bi1 = {bb1, bb1, bb1, bb1};
#define L1G(P0, P1, TF0, TF1)                                                \
    {                                                                        \
      const half8 pa = cat(P0, P1);                                          \
      TF0 = relupk(MF32(pa, m0, bi0));                                       \
      TF1 = relupk(MF32(pa, m1, bi1));                                       \
    }
    L1G(pf00, pf10, tf00, tf01) L1G(pf01, pf11, tf10, tf11)
    L1G(pf02, pf12, tf20, tf21) L1G(pf03, pf13, tf30, tf31)
    L1G(pf04, pf14, tf40, tf41) L1G(pf05, pf15, tf50, tf51)
    L1G(pf06, pf16, tf60, tf61) L1G(pf07, pf17, tf70, tf71)
#undef L1G
  }

  GALL()   // G1
#undef GALL
#undef GSTEP

  // ---- L2 + folded readout ----
  {
    const f16* mbl = mb + 1 * 1024;
    const half8 m0 = *(const half8*)(mbl + (0 * 64 + lane) * 8);
    const half8 m1 = *(const half8*)(mbl + (1 * 64 + lane) * 8);
    const float bb0 = bia[2 * H + lrow], bb1 = bia[2 * H + 16 + lrow];
    const f32x4 bi0 = {bb0, bb0, bb0, bb0};
    const f32x4 bi1 = {bb1, bb1, bb1, bb1};
    const float u0 = u[lrow], u1 = u[16 + lrow];
    float partial = 0.f;
#define L2G(g, P0, P1)                                                       \
    {                                                                        \
      const half8 pa = cat(P0, P1);                                          \
      f32x4 c0 = MF32(pa, m0, bi0);                                          \
      f32x4 c1 = MF32(pa, m1, bi1);                                          \
      const float4 vv = *(const float4*)(v + (g) * 16 + quad * 4);           \
      partial += (fmaxf(c0[0], 0.f) * vv.x + fmaxf(c0[1], 0.f) * vv.y +      \
                  fmaxf(c0[2], 0.f) * vv.z + fmaxf(c0[3], 0.f) * vv.w) * u0 +\
                 (fmaxf(c1[0], 0.f) * vv.x + fmaxf(c1[1], 0.f) * vv.y +      \
                  fmaxf(c1[2], 0.f) * vv.z + fmaxf(c1[3], 0.f) * vv.w) * u1; \
    }
    L2G(0, pf00, pf10) L2G(1, pf01, pf11) L2G(2, pf02, pf12) L2G(3, pf03, pf13)
    L2G(4, pf04, pf14) L2G(5, pf05, pf15) L2G(6, pf06, pf16) L2G(7, pf07, pf17)
#undef L2G
#pragma unroll
    for (int off = 32; off > 0; off >>= 1) partial += __shfl_down(partial, off, 64);
    if (lane == 0) out[b] = partial + cp[0];
  }
}

extern "C" void kernel_launch(void* const* d_in, const int* in_sizes, int n_in,
                              void* d_out, int out_size, void* d_ws, size_t ws_size,
                              hipStream_t stream) {
  const float* x      = (const float*)d_in[0];
  const float* adj    = (const float*)d_in[1];
  const float* W_lift = (const float*)d_in[2];
  const float* b_lift = (const float*)d_in[3];
  const float* W1     = (const float*)d_in[4];
  const float* b1     = (const float*)d_in[5];
  const float* W2     = (const float*)d_in[6];
  const float* b2     = (const float*)d_in[7];
  const float* W_ro   = (const float*)d_in[8];
  const float* b_ro   = (const float*)d_in[9];
  char* ws = (char*)d_ws;
  float* o = (float*)d_out;

  const int B = in_sizes[0] / (N * 3);   // 16384
  hipLaunchKernelGGL(prep, dim3(2), dim3(256), 0, stream,
                     adj, W_lift, b_lift, W1, b1, W2, b2, W_ro, b_ro, ws);
  hipLaunchKernelGGL(gnn_mfma, dim3(B / 4), dim3(256), 0, stream,
                     x, (const char*)ws, o);
}